// Round 14
// baseline (149.599 us; speedup 1.0000x reference)
//
#include <hip/hip_runtime.h>

// PlaceCellNetwork forward — R14 DIRECTION-DECOMPOSITION ROUND.
// R12/R13 converge at 76us (4.6 TB/s app). Remaining unknown: which
// direction binds on THIS buffer set (352MB working set cycling a 256MB IC).
// Probes, all with best technique (DMA stage, NT store, 8 blk/CU):
//   k_read : prev+x -> LDS via global_load_lds, sunk (read-only rate)
//   k_copy : prev -> out via LDS (copy rate, no compute/transpose)
//   k_full : R13 best kernel (LAST -> validation passes)
// Decode: k_copy/k_full from rocprof top-5; k_read from top-5 if slow
// (>55us = read-bound smoking gun) or from timed-total arithmetic if fast.

#define HID 20
#define OUT 10
#define RPB 512                 // rows per block (4 waves x 128 rows)
#define RPW 128                 // rows per wave
#define WSLAB (RPW * OUT)       // 1280 words = 5120 B per wave region

typedef float f32x2 __attribute__((ext_vector_type(2)));
typedef float f32x4 __attribute__((ext_vector_type(4)));
typedef float __attribute__((address_space(1))) as1f;
typedef float __attribute__((address_space(3))) as3f;

__device__ __forceinline__ float fast_rcp(float x) { return __builtin_amdgcn_rcpf(x); }
__device__ __forceinline__ float fast_exp2(float x) { return __builtin_amdgcn_exp2f(x); }
__device__ __forceinline__ f32x2 sp(float s) { return (f32x2){s, s}; }

#define EACH10(F) F(0) F(1) F(2) F(3) F(4) F(5) F(6) F(7) F(8) F(9)
#define PIN(v) asm volatile("" : "+v"(v))

// ---- weight repack (verified layout since R6) ----
__global__ void repack_kernel(const float* __restrict__ Wh, const float* __restrict__ bh,
                              const float* __restrict__ Wo, const float* __restrict__ bo,
                              const float* __restrict__ Wf, float* __restrict__ ws) {
    const float S = 2.8853900817779268f;  // 2*log2(e)
    const float L = 1.4426950408889634f;  // log2(e)
    int t = threadIdx.x;
    if (t < HID) {
        float* b = ws + 24 * t;
        b[0] = S * Wh[3 * t + 0];
        b[1] = S * Wh[3 * t + 1];
        b[2] = S * (Wh[3 * t + 2] + bh[t]);
        b[3] = 0.0f;
        for (int o = 0; o < OUT; ++o) {
            b[4 + o]  = S * Wf[o * HID + t];
            b[14 + o] = -S * Wo[o * HID + t];
        }
    } else if (t < HID + OUT) {
        int o = t - HID;
        float s = bo[o];
        for (int i = 0; i < HID; ++i) s += Wo[o * HID + i];
        ws[480 + o] = L * s;
    }
}

// ---- probe 1: pure read (DMA stage + x loads, sunk) ----
__global__ __launch_bounds__(256, 8) void k_read(
    const float* __restrict__ x, const float* __restrict__ prev, long B) {
    __shared__ float lds[4 * WSLAB];
    const int t = threadIdx.x;
    const int wv = t >> 6, l = t & 63;
    const long wrow = (long)blockIdx.x * RPB + (long)RPW * wv;
    const long rem = B - wrow;
    if (rem <= 0) return;
    const int Vw = (rem < RPW) ? (int)rem : RPW;
    float* slab = lds + WSLAB * wv;

    const float* tsrc = prev + wrow * OUT;
    if (Vw == RPW) {
#pragma unroll
        for (int k = 0; k < 5; ++k) {
            __builtin_amdgcn_global_load_lds(
                (const as1f*)(tsrc + 4 * (64 * k + l)),
                (as3f*)(slab + 256 * k), 16, 0, 0);
        }
    } else {
        for (int f = l; f < Vw * OUT; f += 64) slab[f] = tsrc[f];
    }
    f32x2 xa = {0.0f, 0.0f};
    if (l < Vw) xa = *reinterpret_cast<const f32x2*>(x + 2 * (wrow + l));

    asm volatile("s_waitcnt vmcnt(0)" ::: "memory");
    __builtin_amdgcn_sched_barrier(0);
    float v0 = slab[l], v1 = slab[640 + l];
    asm volatile("" :: "v"(v0), "v"(v1), "v"(xa.x), "v"(xa.y));
}

// ---- probe 2: pure copy prev -> out (DMA stage, NT store, no compute) ----
__global__ __launch_bounds__(256, 8) void k_copy(
    const float* __restrict__ prev, float* __restrict__ out, long B) {
    __shared__ float lds[4 * WSLAB];
    const int t = threadIdx.x;
    const int wv = t >> 6, l = t & 63;
    const long wrow = (long)blockIdx.x * RPB + (long)RPW * wv;
    const long rem = B - wrow;
    if (rem <= 0) return;
    const int Vw = (rem < RPW) ? (int)rem : RPW;
    float* slab = lds + WSLAB * wv;

    const float* tsrc = prev + wrow * OUT;
    float* dst = out + wrow * OUT;
    if (Vw == RPW) {
#pragma unroll
        for (int k = 0; k < 5; ++k) {
            __builtin_amdgcn_global_load_lds(
                (const as1f*)(tsrc + 4 * (64 * k + l)),
                (as3f*)(slab + 256 * k), 16, 0, 0);
        }
        asm volatile("s_waitcnt vmcnt(0)" ::: "memory");
        __builtin_amdgcn_sched_barrier(0);
#pragma unroll
        for (int k = 0; k < 5; ++k) {
            const f32x4 v = *reinterpret_cast<const f32x4*>(slab + 4 * (64 * k + l));
            __builtin_nontemporal_store(v, reinterpret_cast<f32x4*>(dst) + 64 * k + l);
        }
    } else {
        for (int f = l; f < Vw * OUT; f += 64)
            __builtin_nontemporal_store(tsrc[f], dst + f);
    }
}

// ---- k_full: R13 kernel (wave-private spans, DMA, NT), runs LAST ----
__global__ __launch_bounds__(256, 8) void pcn_kernel(
    const float* __restrict__ x, const float* __restrict__ prev,
    const float* __restrict__ w, float* __restrict__ out, long B) {
    __shared__ float lds[4 * WSLAB];     // 20480 B -> 8 blocks/CU
    const int t = threadIdx.x;
    const int wv = t >> 6, l = t & 63;
    const long wrow = (long)blockIdx.x * RPB + (long)RPW * wv;
    const long rem = B - wrow;
    if (rem <= 0) return;
    const int Vw = (rem < RPW) ? (int)rem : RPW;
    float* slab = lds + WSLAB * wv;

    const float* tsrc = prev + wrow * OUT;
    if (Vw == RPW) {
#pragma unroll
        for (int k = 0; k < 5; ++k) {
            __builtin_amdgcn_global_load_lds(
                (const as1f*)(tsrc + 4 * (64 * k + l)),
                (as3f*)(slab + 256 * k), 16, 0, 0);
        }
    } else {
        for (int f = l; f < Vw * OUT; f += 64) slab[f] = tsrc[f];
    }

    const bool aok = l < Vw;
    const bool bok = (64 + l) < Vw;
    f32x2 xa = {0.0f, 0.0f}, xb = {0.0f, 0.0f};
    if (aok) xa = *reinterpret_cast<const f32x2*>(x + 2 * (wrow + l));
    if (bok) xb = *reinterpret_cast<const f32x2*>(x + 2 * (wrow + 64 + l));

    asm volatile("s_waitcnt vmcnt(0)" ::: "memory");
    __builtin_amdgcn_sched_barrier(0);

    const float* ra = slab + 10 * l;
    const float* rb = slab + 10 * (64 + l);
    const f32x2 x0 = {xa.x, xb.x};
    const f32x2 x1 = {xa.y, xb.y};
#define DECLP(o) f32x2 p##o = {ra[o], rb[o]}; PIN(p##o);
    EACH10(DECLP)
#undef DECLP

#define INITL(o) f32x2 l##o = sp(w[480 + o]);
    EACH10(INITL)
#undef INITL
#pragma unroll
    for (int i = 0; i < HID; ++i) {
        const float* wb = w + 24 * i;
        f32x2 a = sp(wb[2]);
        a += sp(wb[0]) * x0;
        a += sp(wb[1]) * x1;
#define FB(o) a += sp(wb[4 + o]) * p##o;
        EACH10(FB)
#undef FB
        f32x2 r;
        r.x = fast_rcp(1.0f + fast_exp2(a.x));
        r.y = fast_rcp(1.0f + fast_exp2(a.y));
#define LO(o) l##o += sp(wb[14 + o]) * r;
        EACH10(LO)
#undef LO
    }
#define EX(o) l##o.x = fast_exp2(l##o.x); l##o.y = fast_exp2(l##o.y);
    EACH10(EX)
#undef EX
    const f32x2 s = ((l0 + l1) + (l2 + l3)) + (((l4 + l5) + (l6 + l7)) + (l8 + l9));
    f32x2 rs;
    rs.x = fast_rcp(s.x);
    rs.y = fast_rcp(s.y);
#define SC(o) l##o *= rs;
    EACH10(SC)
#undef SC

    __builtin_amdgcn_wave_barrier();
    if (aok) {
        f32x2* d = reinterpret_cast<f32x2*>(slab + 10 * l);
        d[0] = (f32x2){l0.x, l1.x}; d[1] = (f32x2){l2.x, l3.x};
        d[2] = (f32x2){l4.x, l5.x}; d[3] = (f32x2){l6.x, l7.x};
        d[4] = (f32x2){l8.x, l9.x};
    }
    if (bok) {
        f32x2* d = reinterpret_cast<f32x2*>(slab + 10 * (64 + l));
        d[0] = (f32x2){l0.y, l1.y}; d[1] = (f32x2){l2.y, l3.y};
        d[2] = (f32x2){l4.y, l5.y}; d[3] = (f32x2){l6.y, l7.y};
        d[4] = (f32x2){l8.y, l9.y};
    }
    __builtin_amdgcn_wave_barrier();

    float* dst = out + wrow * OUT;
    if (Vw == RPW) {
#pragma unroll
        for (int k = 0; k < 5; ++k) {
            const f32x4 v = *reinterpret_cast<const f32x4*>(slab + 4 * (64 * k + l));
            __builtin_nontemporal_store(v, reinterpret_cast<f32x4*>(dst) + 64 * k + l);
        }
    } else {
        for (int f = l; f < Vw * OUT; f += 64)
            __builtin_nontemporal_store(slab[f], dst + f);
    }
}

// ---- fallback (no workspace): 1 row/thread ----
__global__ __launch_bounds__(256) void pcn_fallback(
    const float* __restrict__ x, const float* __restrict__ prev,
    const float* __restrict__ Wh, const float* __restrict__ bh,
    const float* __restrict__ Wo, const float* __restrict__ bo,
    const float* __restrict__ Wf, float* __restrict__ out, long B) {
    const long r = (long)blockIdx.x * blockDim.x + threadIdx.x;
    if (r >= B) return;
    const float x0 = x[2 * r], x1 = x[2 * r + 1];
#define DECLP(o) float p##o = prev[10 * r + o];
    EACH10(DECLP)
#undef DECLP
#define DECLL(o) float l##o = bo[o];
    EACH10(DECLL)
#undef DECLL
#pragma unroll
    for (int i = 0; i < HID; ++i) {
        float a = fmaf(Wh[3 * i], x0, fmaf(Wh[3 * i + 1], x1, Wh[3 * i + 2] + bh[i]));
#define FB(o) a = fmaf(Wf[o * HID + i], p##o, a);
        EACH10(FB)
#undef FB
        const float h = 1.0f - 2.0f * fast_rcp(1.0f + __expf(2.0f * a));
#define LO(o) l##o = fmaf(Wo[o * HID + i], h, l##o);
        EACH10(LO)
#undef LO
    }
    float m = l0;
#define MX(o) m = fmaxf(m, l##o);
    MX(1) MX(2) MX(3) MX(4) MX(5) MX(6) MX(7) MX(8) MX(9)
#undef MX
    float s = 0.0f;
#define EX(o) l##o = __expf(l##o - m); s += l##o;
    EACH10(EX)
#undef EX
    const float rs = fast_rcp(s);
#define ST(o) out[10 * r + o] = l##o * rs;
    EACH10(ST)
#undef ST
}

extern "C" void kernel_launch(void* const* d_in, const int* in_sizes, int n_in,
                              void* d_out, int out_size, void* d_ws, size_t ws_size,
                              hipStream_t stream) {
    const float* x    = (const float*)d_in[0];
    const float* prev = (const float*)d_in[1];
    const float* Wh   = (const float*)d_in[2];
    const float* bh   = (const float*)d_in[3];
    const float* Wo   = (const float*)d_in[4];
    const float* bo   = (const float*)d_in[5];
    const float* Wf   = (const float*)d_in[6];
    float* out = (float*)d_out;

    const long B = in_sizes[0] / 2;
    const int grid = (int)((B + RPB - 1) / RPB);

    if (ws_size >= 490 * sizeof(float)) {
        float* ws = (float*)d_ws;
        repack_kernel<<<1, 64, 0, stream>>>(Wh, bh, Wo, bo, Wf, ws);
        k_read<<<grid, 256, 0, stream>>>(x, prev, B);
        k_copy<<<grid, 256, 0, stream>>>(prev, out, B);
        pcn_kernel<<<grid, 256, 0, stream>>>(x, prev, ws, out, B);  // last
    } else {
        const int gb = (int)((B + 255) / 256);
        pcn_fallback<<<gb, 256, 0, stream>>>(x, prev, Wh, bh, Wo, bo, Wf, out, B);
    }
}

// Round 15
// 139.261 us; speedup vs baseline: 1.0742x; 1.0742x over previous
//
#include <hip/hip_runtime.h>

// PlaceCellNetwork forward: out = softmax(tanh([x,1] @ Wh^T + bh + prev @ Wf) @ Wo^T + bo)
// B=4M, IN=2, HID=20, OUT=10.
//
// R15: WAVE-PRIVATE COUNTED-VMCNT PIPELINE (T3/T4 in miniature).
// R14 decomposition: k_read+k_copy = ~70us for 512MB (7.3 TB/s) -> memory
// directions run at machine rate; k_full's 76us for 352MB has ~26us of
// EXPOSED COMPUTE (matches VALUBusy 38%*76 = 29us). R13's waves are serial:
// DMA -> vmcnt(0) -> compute -> store; no memory in flight during compute.
// This round each wave processes 256 rows as 2 chunks x 2 LDS slabs:
//   stage(c0); stage(c1); vmcnt(7) -> compute c0 (c1 loads in flight);
//   vmcnt(0) -> compute c1; batched NT stores. Loads-only counted waits
//   (stores issued after all waits -> m135-safe); sched_barrier(0) pins
//   issue-group order so "oldest 7" == c0's loads (rule #18).
// LDS 40KB/block -> 4 blocks/CU, 16 waves/CU (80KB reads in flight/CU).
// Compute core unchanged (verified absmax 2e-3 since R3).

#define HID 20
#define OUT 10
#define CROWS 128                // rows per chunk
#define WROWS 256                // rows per wave (2 chunks)
#define RPB 1024                 // rows per block (4 waves)
#define WSLAB (CROWS * OUT)      // 1280 words = 5120 B per chunk slab

typedef float f32x2 __attribute__((ext_vector_type(2)));
typedef float f32x4 __attribute__((ext_vector_type(4)));
typedef float __attribute__((address_space(1))) as1f;
typedef float __attribute__((address_space(3))) as3f;

__device__ __forceinline__ float fast_rcp(float x) { return __builtin_amdgcn_rcpf(x); }
__device__ __forceinline__ float fast_exp2(float x) { return __builtin_amdgcn_exp2f(x); }
__device__ __forceinline__ f32x2 sp(float s) { return (f32x2){s, s}; }

#define EACH10(F) F(0) F(1) F(2) F(3) F(4) F(5) F(6) F(7) F(8) F(9)
#define PIN(v) asm volatile("" : "+v"(v))

// ---- weight repack (verified layout since R6) ----
__global__ void repack_kernel(const float* __restrict__ Wh, const float* __restrict__ bh,
                              const float* __restrict__ Wo, const float* __restrict__ bo,
                              const float* __restrict__ Wf, float* __restrict__ ws) {
    const float S = 2.8853900817779268f;  // 2*log2(e)
    const float L = 1.4426950408889634f;  // log2(e)
    int t = threadIdx.x;
    if (t < HID) {
        float* b = ws + 24 * t;
        b[0] = S * Wh[3 * t + 0];
        b[1] = S * Wh[3 * t + 1];
        b[2] = S * (Wh[3 * t + 2] + bh[t]);
        b[3] = 0.0f;
        for (int o = 0; o < OUT; ++o) {
            b[4 + o]  = S * Wf[o * HID + t];
            b[14 + o] = -S * Wo[o * HID + t];
        }
    } else if (t < HID + OUT) {
        int o = t - HID;
        float s = bo[o];
        for (int i = 0; i < HID; ++i) s += Wo[o * HID + i];
        ws[480 + o] = L * s;
    }
}

// ---- helpers ----
__device__ __forceinline__ void stage128(const float* src, float* slab, int l) {
#pragma unroll
    for (int k = 0; k < 5; ++k) {
        __builtin_amdgcn_global_load_lds(
            (const as1f*)(src + 4 * (64 * k + l)),
            (as3f*)(slab + 256 * k), 16, 0, 0);
    }
}

__device__ __forceinline__ void chunk_compute(
    const float* slab, const float* __restrict__ w, int l,
    const f32x2 xa, const f32x2 xb,
    f32x2& o0, f32x2& o1, f32x2& o2, f32x2& o3, f32x2& o4,
    f32x2& o5, f32x2& o6, f32x2& o7, f32x2& o8, f32x2& o9) {
    const float* ra = slab + 10 * l;
    const float* rb = slab + 10 * (64 + l);
    const f32x2 x0 = {xa.x, xb.x};
    const f32x2 x1 = {xa.y, xb.y};
#define DECLP(o) f32x2 p##o = {ra[o], rb[o]}; PIN(p##o);
    EACH10(DECLP)
#undef DECLP
#define INITL(o) f32x2 l##o = sp(w[480 + o]);
    EACH10(INITL)
#undef INITL
#pragma unroll
    for (int i = 0; i < HID; ++i) {
        const float* wb = w + 24 * i;
        f32x2 a = sp(wb[2]);
        a += sp(wb[0]) * x0;
        a += sp(wb[1]) * x1;
#define FB(o) a += sp(wb[4 + o]) * p##o;
        EACH10(FB)
#undef FB
        f32x2 r;
        r.x = fast_rcp(1.0f + fast_exp2(a.x));
        r.y = fast_rcp(1.0f + fast_exp2(a.y));
#define LO(o) l##o += sp(wb[14 + o]) * r;
        EACH10(LO)
#undef LO
    }
#define EX(o) l##o.x = fast_exp2(l##o.x); l##o.y = fast_exp2(l##o.y);
    EACH10(EX)
#undef EX
    const f32x2 s = ((l0 + l1) + (l2 + l3)) + (((l4 + l5) + (l6 + l7)) + (l8 + l9));
    f32x2 rs;
    rs.x = fast_rcp(s.x);
    rs.y = fast_rcp(s.y);
    o0 = l0 * rs; o1 = l1 * rs; o2 = l2 * rs; o3 = l3 * rs; o4 = l4 * rs;
    o5 = l5 * rs; o6 = l6 * rs; o7 = l7 * rs; o8 = l8 * rs; o9 = l9 * rs;
}

__device__ __forceinline__ void restage_rows(
    float* slab, int l, bool aok, bool bok,
    const f32x2 o0, const f32x2 o1, const f32x2 o2, const f32x2 o3, const f32x2 o4,
    const f32x2 o5, const f32x2 o6, const f32x2 o7, const f32x2 o8, const f32x2 o9) {
    if (aok) {
        f32x2* d = reinterpret_cast<f32x2*>(slab + 10 * l);
        d[0] = (f32x2){o0.x, o1.x}; d[1] = (f32x2){o2.x, o3.x};
        d[2] = (f32x2){o4.x, o5.x}; d[3] = (f32x2){o6.x, o7.x};
        d[4] = (f32x2){o8.x, o9.x};
    }
    if (bok) {
        f32x2* d = reinterpret_cast<f32x2*>(slab + 10 * (64 + l));
        d[0] = (f32x2){o0.y, o1.y}; d[1] = (f32x2){o2.y, o3.y};
        d[2] = (f32x2){o4.y, o5.y}; d[3] = (f32x2){o6.y, o7.y};
        d[4] = (f32x2){o8.y, o9.y};
    }
}

__device__ __forceinline__ void store_slab128(const float* slab, float* dst, int l) {
#pragma unroll
    for (int k = 0; k < 5; ++k) {
        const f32x4 v = *reinterpret_cast<const f32x4*>(slab + 4 * (64 * k + l));
        __builtin_nontemporal_store(v, reinterpret_cast<f32x4*>(dst) + 64 * k + l);
    }
}

// generic (tail) chunk: conservative vmcnt(0), guarded everything
__device__ void generic_chunk(const float* __restrict__ x, const float* __restrict__ prev,
                              const float* __restrict__ w, float* __restrict__ out,
                              long cbase, long B, float* slab, int l) {
    const long rem = B - cbase;
    if (rem <= 0) return;
    const int V = (rem < CROWS) ? (int)rem : CROWS;
    const float* tsrc = prev + cbase * OUT;
    if (V == CROWS) {
        stage128(tsrc, slab, l);
    } else {
        for (int f = l; f < V * OUT; f += 64) slab[f] = tsrc[f];
    }
    const bool aok = l < V;
    const bool bok = (64 + l) < V;
    f32x2 xa = {0.0f, 0.0f}, xb = {0.0f, 0.0f};
    if (aok) xa = *reinterpret_cast<const f32x2*>(x + 2 * (cbase + l));
    if (bok) xb = *reinterpret_cast<const f32x2*>(x + 2 * (cbase + 64 + l));
    asm volatile("s_waitcnt vmcnt(0)" ::: "memory");
    __builtin_amdgcn_sched_barrier(0);
    f32x2 o0, o1, o2, o3, o4, o5, o6, o7, o8, o9;
    chunk_compute(slab, w, l, xa, xb, o0, o1, o2, o3, o4, o5, o6, o7, o8, o9);
    __builtin_amdgcn_wave_barrier();
    restage_rows(slab, l, aok, bok, o0, o1, o2, o3, o4, o5, o6, o7, o8, o9);
    __builtin_amdgcn_wave_barrier();
    float* dst = out + cbase * OUT;
    if (V == CROWS) {
        store_slab128(slab, dst, l);
    } else {
        for (int f = l; f < V * OUT; f += 64)
            __builtin_nontemporal_store(slab[f], dst + f);
    }
}

// ---- main kernel: 2-chunk counted-vmcnt pipeline per wave ----
__global__ __launch_bounds__(256, 4) void pcn_kernel(
    const float* __restrict__ x, const float* __restrict__ prev,
    const float* __restrict__ w, float* __restrict__ out, long B) {
    __shared__ float lds[4][2][WSLAB];   // 40960 B -> 4 blocks/CU, 16 waves/CU
    const int t = threadIdx.x;
    const int wv = t >> 6, l = t & 63;
    const long wrow = (long)blockIdx.x * RPB + (long)WROWS * wv;
    if (wrow >= B) return;
    float* sA = &lds[wv][0][0];
    float* sB = &lds[wv][1][0];
    const long c0 = wrow, c1 = wrow + CROWS;

    if (B - c1 >= CROWS) {
        // ---- fast path: both chunks full (all waves when B%256==0) ----
        // issue group 0: chunk0 loads (5 DMA + 2 x = 7 vmem ops)
        stage128(prev + c0 * OUT, sA, l);
        f32x2 xa0 = *reinterpret_cast<const f32x2*>(x + 2 * (c0 + l));
        f32x2 xb0 = *reinterpret_cast<const f32x2*>(x + 2 * (c0 + 64 + l));
        __builtin_amdgcn_sched_barrier(0);
        // issue group 1: chunk1 loads (7 vmem ops)
        stage128(prev + c1 * OUT, sB, l);
        f32x2 xa1 = *reinterpret_cast<const f32x2*>(x + 2 * (c1 + l));
        f32x2 xb1 = *reinterpret_cast<const f32x2*>(x + 2 * (c1 + 64 + l));
        __builtin_amdgcn_sched_barrier(0);

        // wait chunk0 only (oldest 7 of 14; loads-only FIFO, m135 semantics)
        asm volatile("s_waitcnt vmcnt(7)" ::: "memory");
        __builtin_amdgcn_sched_barrier(0);
        f32x2 a0, a1, a2, a3, a4, a5, a6, a7, a8, a9;
        chunk_compute(sA, w, l, xa0, xb0, a0, a1, a2, a3, a4, a5, a6, a7, a8, a9);
        __builtin_amdgcn_wave_barrier();
        restage_rows(sA, l, true, true, a0, a1, a2, a3, a4, a5, a6, a7, a8, a9);

        // wait chunk1 (arrived during chunk0 compute)
        asm volatile("s_waitcnt vmcnt(0)" ::: "memory");
        __builtin_amdgcn_sched_barrier(0);
        f32x2 b0, b1, b2, b3, b4, b5, b6, b7, b8, b9;
        chunk_compute(sB, w, l, xa1, xb1, b0, b1, b2, b3, b4, b5, b6, b7, b8, b9);
        __builtin_amdgcn_wave_barrier();
        restage_rows(sB, l, true, true, b0, b1, b2, b3, b4, b5, b6, b7, b8, b9);
        __builtin_amdgcn_wave_barrier();

        // batched NT copy-out: 10KB contiguous per wave
        store_slab128(sA, out + c0 * OUT, l);
        store_slab128(sB, out + c1 * OUT, l);
    } else {
        // ---- tail path (at most one wave in the grid) ----
        generic_chunk(x, prev, w, out, c0, B, sA, l);
        generic_chunk(x, prev, w, out, c1, B, sB, l);
    }
}

// ---- fallback (no workspace): 1 row/thread ----
__global__ __launch_bounds__(256) void pcn_fallback(
    const float* __restrict__ x, const float* __restrict__ prev,
    const float* __restrict__ Wh, const float* __restrict__ bh,
    const float* __restrict__ Wo, const float* __restrict__ bo,
    const float* __restrict__ Wf, float* __restrict__ out, long B) {
    const long r = (long)blockIdx.x * blockDim.x + threadIdx.x;
    if (r >= B) return;
    const float x0 = x[2 * r], x1 = x[2 * r + 1];
#define DECLP(o) float p##o = prev[10 * r + o];
    EACH10(DECLP)
#undef DECLP
#define DECLL(o) float l##o = bo[o];
    EACH10(DECLL)
#undef DECLL
#pragma unroll
    for (int i = 0; i < HID; ++i) {
        float a = fmaf(Wh[3 * i], x0, fmaf(Wh[3 * i + 1], x1, Wh[3 * i + 2] + bh[i]));
#define FB(o) a = fmaf(Wf[o * HID + i], p##o, a);
        EACH10(FB)
#undef FB
        const float h = 1.0f - 2.0f * fast_rcp(1.0f + __expf(2.0f * a));
#define LO(o) l##o = fmaf(Wo[o * HID + i], h, l##o);
        EACH10(LO)
#undef LO
    }
    float m = l0;
#define MX(o) m = fmaxf(m, l##o);
    MX(1) MX(2) MX(3) MX(4) MX(5) MX(6) MX(7) MX(8) MX(9)
#undef MX
    float s = 0.0f;
#define EX(o) l##o = __expf(l##o - m); s += l##o;
    EACH10(EX)
#undef EX
    const float rs = fast_rcp(s);
#define ST(o) out[10 * r + o] = l##o * rs;
    EACH10(ST)
#undef ST
}

extern "C" void kernel_launch(void* const* d_in, const int* in_sizes, int n_in,
                              void* d_out, int out_size, void* d_ws, size_t ws_size,
                              hipStream_t stream) {
    const float* x    = (const float*)d_in[0];
    const float* prev = (const float*)d_in[1];
    const float* Wh   = (const float*)d_in[2];
    const float* bh   = (const float*)d_in[3];
    const float* Wo   = (const float*)d_in[4];
    const float* bo   = (const float*)d_in[5];
    const float* Wf   = (const float*)d_in[6];
    float* out = (float*)d_out;

    const long B = in_sizes[0] / 2;

    if (ws_size >= 490 * sizeof(float)) {
        float* ws = (float*)d_ws;
        repack_kernel<<<1, 64, 0, stream>>>(Wh, bh, Wo, bo, Wf, ws);
        const int grid = (int)((B + RPB - 1) / RPB);
        pcn_kernel<<<grid, 256, 0, stream>>>(x, prev, ws, out, B);
    } else {
        const int gb = (int)((B + 255) / 256);
        pcn_fallback<<<gb, 256, 0, stream>>>(x, prev, Wh, bh, Wo, bo, Wf, out, B);
    }
}

// Round 16
// 73.858 us; speedup vs baseline: 2.0255x; 1.8855x over previous
//
#include <hip/hip_runtime.h>

// PlaceCellNetwork forward: out = softmax(tanh([x,1] @ Wh^T + bh + prev @ Wf) @ Wo^T + bo)
// B=4M, IN=2, HID=20, OUT=10.
//
// R16 = R13 champion (76us: wave-private spans, DMA staging, NT stores,
// 8 blocks/CU) + COHORT PHASE-STAGGER. R14 proved the memory system does
// ~7 TB/s on this buffer set with zero compute (k_copy); k_full's extra
// ~28us equals its VALU time -> compute is ADDITIVE, i.e. memory and
// compute phases never overlap ACROSS waves. Only mechanism found: all 8
// resident blocks/CU (blockIdx c, c+256, ..., c+1792) launch together, run
// identical ~2us bodies, and stay phase-locked (collective stage -> memory
// burst/VALU idle -> collective compute -> memory idle). Fix under test:
// stagger cohort k = (blockIdx>>8)&7 by k*~0.21us via s_sleep at entry.
// One-time cost <=1.5us; successors inherit offsets.
// If null -> phase theory dead, ~76us = practical wall, declare roofline.
//
// Compute core unchanged (verified absmax 2e-3 since R3):
//   a'' = 2*log2e*(Wh x + bh + Wf^T prev);  r = rcp(1+2^a'')
//   l'  = log2e*(bo+rowsum(Wo)) - 2*log2e*Wo . r ;  out = 2^l' / sum(2^l')

#define HID 20
#define OUT 10
#define RPB 512                 // rows per block (4 waves x 128 rows)
#define RPW 128                 // rows per wave
#define WSLAB (RPW * OUT)       // 1280 words = 5120 B per wave region

typedef float f32x2 __attribute__((ext_vector_type(2)));
typedef float f32x4 __attribute__((ext_vector_type(4)));
typedef float __attribute__((address_space(1))) as1f;
typedef float __attribute__((address_space(3))) as3f;

__device__ __forceinline__ float fast_rcp(float x) { return __builtin_amdgcn_rcpf(x); }
__device__ __forceinline__ float fast_exp2(float x) { return __builtin_amdgcn_exp2f(x); }
__device__ __forceinline__ f32x2 sp(float s) { return (f32x2){s, s}; }

#define EACH10(F) F(0) F(1) F(2) F(3) F(4) F(5) F(6) F(7) F(8) F(9)
#define PIN(v) asm volatile("" : "+v"(v))

// ---- weight repack (verified layout since R6) ----
__global__ void repack_kernel(const float* __restrict__ Wh, const float* __restrict__ bh,
                              const float* __restrict__ Wo, const float* __restrict__ bo,
                              const float* __restrict__ Wf, float* __restrict__ ws) {
    const float S = 2.8853900817779268f;  // 2*log2(e)
    const float L = 1.4426950408889634f;  // log2(e)
    int t = threadIdx.x;
    if (t < HID) {
        float* b = ws + 24 * t;
        b[0] = S * Wh[3 * t + 0];
        b[1] = S * Wh[3 * t + 1];
        b[2] = S * (Wh[3 * t + 2] + bh[t]);
        b[3] = 0.0f;
        for (int o = 0; o < OUT; ++o) {
            b[4 + o]  = S * Wf[o * HID + t];
            b[14 + o] = -S * Wo[o * HID + t];
        }
    } else if (t < HID + OUT) {
        int o = t - HID;
        float s = bo[o];
        for (int i = 0; i < HID; ++i) s += Wo[o * HID + i];
        ws[480 + o] = L * s;
    }
}

// ---- main kernel: R13 + cohort stagger ----
__global__ __launch_bounds__(256, 8) void pcn_kernel(
    const float* __restrict__ x, const float* __restrict__ prev,
    const float* __restrict__ w, float* __restrict__ out, long B) {
    __shared__ float lds[4 * WSLAB];     // 20480 B -> 8 blocks/CU, 32 waves/CU
    const int t = threadIdx.x;
    const int wv = t >> 6, l = t & 63;

    // ---- cohort phase-stagger: blocks c, c+256, ..., c+1792 co-reside on
    // one CU; offset cohort k by k * ~512cy*? (s_sleep(8) ~ 8*64 = 512 cy
    // ~0.21us) to break stage/compute phase lockstep. One-time cost. ----
    {
        const int cohort = (int)((blockIdx.x >> 8) & 7);
#pragma unroll 1
        for (int i = 0; i < cohort; ++i) __builtin_amdgcn_s_sleep(8);
    }

    const long wrow = (long)blockIdx.x * RPB + (long)RPW * wv;  // wave's 1st row
    const long rem = B - wrow;
    if (rem <= 0) return;                       // empty tail wave
    const int Vw = (rem < RPW) ? (int)rem : RPW;
    float* slab = lds + WSLAB * wv;

    // ---- stage own 128-row span: 5x global_load_lds (1KB each, no VGPRs) ----
    const float* tsrc = prev + wrow * OUT;
    if (Vw == RPW) {
#pragma unroll
        for (int k = 0; k < 5; ++k) {
            __builtin_amdgcn_global_load_lds(
                (const as1f*)(tsrc + 4 * (64 * k + l)),   // per-lane global src
                (as3f*)(slab + 256 * k),                  // wave-uniform dest
                16, 0, 0);
        }
    } else {
        for (int f = l; f < Vw * OUT; f += 64) slab[f] = tsrc[f];  // rare tail
    }

    // ---- x loads issued under the DMA latency (dense 8B) ----
    const bool aok = l < Vw;
    const bool bok = (64 + l) < Vw;
    f32x2 xa = {0.0f, 0.0f}, xb = {0.0f, 0.0f};
    if (aok) xa = *reinterpret_cast<const f32x2*>(x + 2 * (wrow + l));
    if (bok) xb = *reinterpret_cast<const f32x2*>(x + 2 * (wrow + 64 + l));

    // ---- wait own loads; fence scheduler (compiler can't see DMA->LDS dep) ----
    asm volatile("s_waitcnt vmcnt(0)" ::: "memory");
    __builtin_amdgcn_sched_barrier(0);

    // ---- rows (wrow+l, wrow+64+l) from own slab (4-way conflict, hidden) ----
    const float* ra = slab + 10 * l;
    const float* rb = slab + 10 * (64 + l);
    const f32x2 x0 = {xa.x, xb.x};
    const f32x2 x1 = {xa.y, xb.y};
#define DECLP(o) f32x2 p##o = {ra[o], rb[o]}; PIN(p##o);
    EACH10(DECLP)
#undef DECLP

    // ---- packed f32x2 compute (verified core) ----
#define INITL(o) f32x2 l##o = sp(w[480 + o]);
    EACH10(INITL)
#undef INITL
#pragma unroll
    for (int i = 0; i < HID; ++i) {
        const float* wb = w + 24 * i;
        f32x2 a = sp(wb[2]);
        a += sp(wb[0]) * x0;
        a += sp(wb[1]) * x1;
#define FB(o) a += sp(wb[4 + o]) * p##o;
        EACH10(FB)
#undef FB
        f32x2 r;
        r.x = fast_rcp(1.0f + fast_exp2(a.x));
        r.y = fast_rcp(1.0f + fast_exp2(a.y));
#define LO(o) l##o += sp(wb[14 + o]) * r;
        EACH10(LO)
#undef LO
    }
#define EX(o) l##o.x = fast_exp2(l##o.x); l##o.y = fast_exp2(l##o.y);
    EACH10(EX)
#undef EX
    const f32x2 s = ((l0 + l1) + (l2 + l3)) + (((l4 + l5) + (l6 + l7)) + (l8 + l9));
    f32x2 rs;
    rs.x = fast_rcp(s.x);
    rs.y = fast_rcp(s.y);
#define SC(o) l##o *= rs;
    EACH10(SC)
#undef SC

    // ---- results -> own slab (dense rows); wave-internal ordering only ----
    __builtin_amdgcn_wave_barrier();
    if (aok) {
        f32x2* d = reinterpret_cast<f32x2*>(slab + 10 * l);
        d[0] = (f32x2){l0.x, l1.x}; d[1] = (f32x2){l2.x, l3.x};
        d[2] = (f32x2){l4.x, l5.x}; d[3] = (f32x2){l6.x, l7.x};
        d[4] = (f32x2){l8.x, l9.x};
    }
    if (bok) {
        f32x2* d = reinterpret_cast<f32x2*>(slab + 10 * (64 + l));
        d[0] = (f32x2){l0.y, l1.y}; d[1] = (f32x2){l2.y, l3.y};
        d[2] = (f32x2){l4.y, l5.y}; d[3] = (f32x2){l6.y, l7.y};
        d[4] = (f32x2){l8.y, l9.y};
    }
    __builtin_amdgcn_wave_barrier();

    // ---- dense NT store of own span (5x 1KB per wave) ----
    float* dst = out + wrow * OUT;
    if (Vw == RPW) {
#pragma unroll
        for (int k = 0; k < 5; ++k) {
            const f32x4 v = *reinterpret_cast<const f32x4*>(slab + 4 * (64 * k + l));
            __builtin_nontemporal_store(v, reinterpret_cast<f32x4*>(dst) + 64 * k + l);
        }
    } else {
        for (int f = l; f < Vw * OUT; f += 64)
            __builtin_nontemporal_store(slab[f], dst + f);
    }
}

// ---- fallback (no workspace): 1 row/thread ----
__global__ __launch_bounds__(256) void pcn_fallback(
    const float* __restrict__ x, const float* __restrict__ prev,
    const float* __restrict__ Wh, const float* __restrict__ bh,
    const float* __restrict__ Wo, const float* __restrict__ bo,
    const float* __restrict__ Wf, float* __restrict__ out, long B) {
    const long r = (long)blockIdx.x * blockDim.x + threadIdx.x;
    if (r >= B) return;
    const float x0 = x[2 * r], x1 = x[2 * r + 1];
#define DECLP(o) float p##o = prev[10 * r + o];
    EACH10(DECLP)
#undef DECLP
#define DECLL(o) float l##o = bo[o];
    EACH10(DECLL)
#undef DECLL
#pragma unroll
    for (int i = 0; i < HID; ++i) {
        float a = fmaf(Wh[3 * i], x0, fmaf(Wh[3 * i + 1], x1, Wh[3 * i + 2] + bh[i]));
#define FB(o) a = fmaf(Wf[o * HID + i], p##o, a);
        EACH10(FB)
#undef FB
        const float h = 1.0f - 2.0f * fast_rcp(1.0f + __expf(2.0f * a));
#define LO(o) l##o = fmaf(Wo[o * HID + i], h, l##o);
        EACH10(LO)
#undef LO
    }
    float m = l0;
#define MX(o) m = fmaxf(m, l##o);
    MX(1) MX(2) MX(3) MX(4) MX(5) MX(6) MX(7) MX(8) MX(9)
#undef MX
    float s = 0.0f;
#define EX(o) l##o = __expf(l##o - m); s += l##o;
    EACH10(EX)
#undef EX
    const float rs = fast_rcp(s);
#define ST(o) out[10 * r + o] = l##o * rs;
    EACH10(ST)
#undef ST
}

extern "C" void kernel_launch(void* const* d_in, const int* in_sizes, int n_in,
                              void* d_out, int out_size, void* d_ws, size_t ws_size,
                              hipStream_t stream) {
    const float* x    = (const float*)d_in[0];
    const float* prev = (const float*)d_in[1];
    const float* Wh   = (const float*)d_in[2];
    const float* bh   = (const float*)d_in[3];
    const float* Wo   = (const float*)d_in[4];
    const float* bo   = (const float*)d_in[5];
    const float* Wf   = (const float*)d_in[6];
    float* out = (float*)d_out;

    const long B = in_sizes[0] / 2;

    if (ws_size >= 490 * sizeof(float)) {
        float* ws = (float*)d_ws;
        repack_kernel<<<1, 64, 0, stream>>>(Wh, bh, Wo, bo, Wf, ws);
        const int grid = (int)((B + RPB - 1) / RPB);
        pcn_kernel<<<grid, 256, 0, stream>>>(x, prev, ws, out, B);
    } else {
        const int gb = (int)((B + 255) / 256);
        pcn_fallback<<<gb, 256, 0, stream>>>(x, prev, Wh, bh, Wo, bo, Wf, out, B);
    }
}